// Round 9
// baseline (74.755 us; speedup 1.0000x reference)
//
#include <hip/hip_runtime.h>
#include <math.h>

// TrackCrossAttention, 3-kernel form:
//   wqkT[n=h*64+d][i] = sum_e wq[i][h*64+e]*wk[d][h*64+e]   (bf16, transposed)
//   bqk[n]            = sum_e bq[h*64+e]*wk[d][h*64+e]
//   wvoT[j][h*64+d]   = sum_e wv[d][h*64+e]*wo[h*64+e][j]   (bf16, transposed)
//   bvo[j]            = sum_e bv[e]*wo[e][j] + bo[j]
// kprep(192+2048): weight folding + RMSNorm->xnb bf16.
// kFA(512): GEMM1 (xnb @ wqkT + bqk)*0.125 -> QW LDS -> per-wave attention tail
//           (tf dbuf via gl_lds16 + counted vmcnt, no block barriers) -> wtfb.
// kG2(512): out = x + wtf @ wvoT + bvo.

#define NTOK 8192

typedef __attribute__((ext_vector_type(8))) short short8;
typedef __attribute__((ext_vector_type(8))) unsigned short ushort8;
typedef __attribute__((ext_vector_type(4))) unsigned short ushort4v;
typedef __attribute__((ext_vector_type(4))) float f32x4;

__device__ __forceinline__ unsigned short f2bf(float f) {
    unsigned int u = __float_as_uint(f);
    unsigned int r = (u + 0x7fffu + ((u >> 16) & 1u)) >> 16;
    return (unsigned short)r;
}
__device__ __forceinline__ float bf2f(unsigned short s) {
    return __uint_as_float(((unsigned int)s) << 16);
}
__device__ __forceinline__ void gl_lds16(const void* g, void* l) {
    __builtin_amdgcn_global_load_lds(
        (const __attribute__((address_space(1))) unsigned int*)g,
        (__attribute__((address_space(3))) unsigned int*)l,
        16, 0, 0);
}

// ---------------- fused prep: weight folding + RMSNorm ----------------

__global__ __launch_bounds__(256) void kprep(
    const float* __restrict__ x, const float* __restrict__ nscale,
    const float* __restrict__ wq, const float* __restrict__ bq,
    const float* __restrict__ wk, const float* __restrict__ wv,
    const float* __restrict__ bv, const float* __restrict__ wo,
    const float* __restrict__ bo,
    unsigned short* __restrict__ wqkT, float* __restrict__ bqk,
    unsigned short* __restrict__ wvoT, float* __restrict__ bvo,
    unsigned short* __restrict__ xnb)
{
    const int bid = blockIdx.x;
    const int t = threadIdx.x;
    if (bid < 64) {
        __shared__ float wkL[64][65];
        __shared__ float wqL[64][65];
        const int h = bid >> 3;
        const int i0 = (bid & 7) * 64;
        #pragma unroll
        for (int i = 0; i < 16; ++i) {
            const int idx = t + i * 256;
            const int d = idx >> 6, e = idx & 63;
            wkL[d][e] = wk[(size_t)d * 512 + h * 64 + e];
            wqL[d][e] = wq[(size_t)(i0 + d) * 512 + h * 64 + e];
        }
        __syncthreads();
        const int d = t & 63, ig = t >> 6;
        float acc[16];
        #pragma unroll
        for (int ii = 0; ii < 16; ++ii) acc[ii] = 0.f;
        for (int e = 0; e < 64; ++e) {
            const float kv = wkL[d][e];
            #pragma unroll
            for (int ii = 0; ii < 16; ++ii)
                acc[ii] += kv * wqL[ig * 16 + ii][e];
        }
        #pragma unroll
        for (int ii = 0; ii < 16; ++ii)
            wqkT[(size_t)(h * 64 + d) * 512 + i0 + ig * 16 + ii] = f2bf(acc[ii]);
        if (((bid & 7) == 0) && ig == 0) {
            float a = 0.f;
            #pragma unroll
            for (int e = 0; e < 64; ++e) a += bq[h * 64 + e] * wkL[d][e];
            bqk[h * 64 + d] = a;
        }
    } else if (bid < 128) {
        __shared__ float wvL[64][65];
        __shared__ float woL[64][65];
        const int b2 = bid - 64;
        const int h = b2 >> 3;
        const int j0 = (b2 & 7) * 64;
        #pragma unroll
        for (int i = 0; i < 16; ++i) {
            const int idx = t + i * 256;
            const int a = idx >> 6, b = idx & 63;
            wvL[a][b] = wv[(size_t)a * 512 + h * 64 + b];
            woL[a][b] = wo[(size_t)(h * 64 + a) * 512 + j0 + b];
        }
        __syncthreads();
        const int jloc = t & 63, dg = t >> 6;
        float acc[16];
        #pragma unroll
        for (int dd = 0; dd < 16; ++dd) acc[dd] = 0.f;
        for (int e = 0; e < 64; ++e) {
            const float b = woL[e][jloc];
            #pragma unroll
            for (int dd = 0; dd < 16; ++dd)
                acc[dd] += wvL[dg * 16 + dd][e] * b;
        }
        #pragma unroll
        for (int dd = 0; dd < 16; ++dd)
            wvoT[(size_t)(j0 + jloc) * 512 + h * 64 + dg * 16 + dd] = f2bf(acc[dd]);
    } else if (bid < 192) {
        const int b3 = bid - 128;
        const int j = b3 * 8 + (t >> 5);
        const int l = t & 31;
        float p = 0.f;
        #pragma unroll 4
        for (int e = l; e < 512; e += 32) p += bv[e] * wo[(size_t)e * 512 + j];
        #pragma unroll
        for (int m = 1; m < 32; m <<= 1) p += __shfl_xor(p, m, 64);
        if (l == 0) bvo[j] = bo[j] + p;
    } else {
        const int row = (bid - 192) * 4 + (t >> 6);
        const int lane = t & 63;
        const float* xr = x + (size_t)row * 512 + lane * 8;
        const float4 v0 = *reinterpret_cast<const float4*>(xr);
        const float4 v1 = *reinterpret_cast<const float4*>(xr + 4);
        float s = v0.x*v0.x + v0.y*v0.y + v0.z*v0.z + v0.w*v0.w
                + v1.x*v1.x + v1.y*v1.y + v1.z*v1.z + v1.w*v1.w;
        #pragma unroll
        for (int m = 1; m < 64; m <<= 1) s += __shfl_xor(s, m, 64);
        const float r = rsqrtf(s * (1.f / 512.f) + 1e-6f);
        const float4 s0 = *reinterpret_cast<const float4*>(nscale + lane * 8);
        const float4 s1 = *reinterpret_cast<const float4*>(nscale + lane * 8 + 4);
        ushort8 o;
        o[0] = f2bf(v0.x * r * s0.x); o[1] = f2bf(v0.y * r * s0.y);
        o[2] = f2bf(v0.z * r * s0.z); o[3] = f2bf(v0.w * r * s0.w);
        o[4] = f2bf(v1.x * r * s1.x); o[5] = f2bf(v1.y * r * s1.y);
        o[6] = f2bf(v1.z * r * s1.z); o[7] = f2bf(v1.w * r * s1.w);
        *reinterpret_cast<ushort8*>(xnb + (size_t)row * 512 + lane * 8) = o;
    }
}

// ---------------- kFA: GEMM1 + per-wave attention tail ----------------
// pool map: GEMM  Asm[2][16K] at [0,32K), Bsm[2][8K] at [32K,48K)
//           tail  QW 128 rows x 160B at [0,20480), TF 4 waves x 2 x 4K at [20480,53248)
// (QW/TF regions only written after the K-loop's final barrier.)

__global__ __launch_bounds__(256) void kFA(
    const unsigned short* __restrict__ A,
    const unsigned short* __restrict__ Bt,
    const float* __restrict__ bqk,
    const float* __restrict__ track,
    unsigned short* __restrict__ wtfb)
{
    __shared__ __align__(16) char pool[53248];
    const int tid = threadIdx.x;
    const int hw = blockIdx.x;
    const int logical = (hw & 7) * 64 + (hw >> 3);   // XCD swizzle (512 % 8 == 0)
    const int mt = logical >> 3, nt = logical & 7;
    const int tok0 = mt * 128, n0 = nt * 64;
    const int w = tid >> 6, lane = tid & 63;
    const int wr = w >> 1, wc = w & 1;
    const int lrow = lane & 15, lk = lane >> 4;

    float pb[2];
    #pragma unroll
    for (int n = 0; n < 2; ++n) pb[n] = bqk[n0 + wc * 32 + n * 16 + lrow];

    const int srowA[4] = { (tid + 0) >> 3, (tid + 256) >> 3, (tid + 512) >> 3, (tid + 768) >> 3 };
    const int sc8 = tid & 7;
    auto STAGE = [&](int buf, int k0) {
        #pragma unroll
        for (int i = 0; i < 4; ++i) {
            const int f = tid + i * 256;
            const int row = srowA[i];
            const int c8s = sc8 ^ (row & 7);
            gl_lds16(A + (size_t)(tok0 + row) * 512 + k0 + c8s * 8,
                     pool + buf * 16384 + f * 16);
        }
        #pragma unroll
        for (int i = 0; i < 2; ++i) {
            const int f = tid + i * 256;
            const int row = f >> 3;
            const int c8s = sc8 ^ (row & 7);
            gl_lds16(Bt + (size_t)(n0 + row) * 512 + k0 + c8s * 8,
                     pool + 32768 + buf * 8192 + f * 16);
        }
    };

    f32x4 acc[4][2] = {};
    STAGE(0, 0);
    __syncthreads();
    for (int it = 0; it < 8; ++it) {
        const int cur = it & 1;
        if (it < 7) STAGE(cur ^ 1, (it + 1) * 64);
        #pragma unroll
        for (int kk = 0; kk < 2; ++kk) {
            short8 a[4], b[2];
            #pragma unroll
            for (int m = 0; m < 4; ++m) {
                const int r = wr * 64 + m * 16 + lrow;
                const int byte = (r * 128 + kk * 64 + lk * 16) ^ ((r & 7) << 4);
                a[m] = *reinterpret_cast<const short8*>(pool + cur * 16384 + byte);
            }
            #pragma unroll
            for (int n = 0; n < 2; ++n) {
                const int r = wc * 32 + n * 16 + lrow;
                const int byte = (r * 128 + kk * 64 + lk * 16) ^ ((r & 7) << 4);
                b[n] = *reinterpret_cast<const short8*>(pool + 32768 + cur * 8192 + byte);
            }
            #pragma unroll
            for (int m = 0; m < 4; ++m)
                #pragma unroll
                for (int n = 0; n < 2; ++n)
                    acc[m][n] = __builtin_amdgcn_mfma_f32_16x16x32_bf16(
                        a[m], b[n], acc[m][n], 0, 0, 0);
        }
        __syncthreads();
    }

    // ---- attention tail ----
    char* TFw = pool + 20480 + w * 8192;
    auto issueTF = [&](int b, int tokloc) {
        const int token = tok0 + tokloc;
        const int bb = token >> 12, cc = token & 4095;   // C = 4096
        char* base = TFw + b * 4096;
        #pragma unroll
        for (int q = 0; q < 4; ++q) {
            const int f = lane + q * 64;
            const int t = f >> 4, ch = f & 15;
            const int chs = ch ^ (t & 7);                 // source-side swizzle (rule #21)
            gl_lds16(track + ((size_t)(bb * 16 + t) * 4096 + cc) * 64 + chs * 4,
                     base + f * 16);
        }
    };
    issueTF(0, w * 32);   // prefetch wave's first token, flies under epilogue

    // epilogue: QW = bf16((acc + bqk) * 0.125), rows stride 160B
    #pragma unroll
    for (int n = 0; n < 2; ++n) {
        const int col = wc * 32 + n * 16 + lrow;
        #pragma unroll
        for (int m = 0; m < 4; ++m) {
            #pragma unroll
            for (int r2 = 0; r2 < 4; ++r2) {
                const int row = wr * 64 + m * 16 + lk * 4 + r2;
                *reinterpret_cast<unsigned short*>(pool + row * 160 + col * 2) =
                    f2bf((acc[m][n][r2] + pb[n]) * 0.125f);
            }
        }
    }
    __syncthreads();   // QW visible to all waves; drains prefetch vmcnt (prologue only)

    const int tp = lane & 15, rep = lane >> 4;
    const int pvch = lane >> 2, pvsub = lane & 3;
    for (int i = 0; i < 32; ++i) {
        if (i < 31) {
            issueTF((i + 1) & 1, w * 32 + i + 1);
            asm volatile("s_waitcnt vmcnt(4)" ::: "memory");
        } else {
            asm volatile("s_waitcnt vmcnt(0)" ::: "memory");
        }
        __builtin_amdgcn_sched_barrier(0);
        const char* tb = TFw + (i & 1) * 4096;
        const int row = w * 32 + i;
        // qf: 16 floats of qw[row][rep*16 .. +15] (broadcast within t-group)
        float qf[16];
        #pragma unroll
        for (int jq = 0; jq < 2; ++jq) {
            const ushort8 qv = *reinterpret_cast<const ushort8*>(
                pool + row * 160 + (rep * 2 + jq) * 16);
            #pragma unroll
            for (int e = 0; e < 8; ++e) qf[jq * 8 + e] = bf2f((unsigned short)qv[e]);
        }
        // logit partial over 16 d for t' = tp
        float a1 = 0.f;
        #pragma unroll
        for (int qq = 0; qq < 4; ++qq) {
            const float4 tv = *reinterpret_cast<const float4*>(
                tb + tp * 256 + (((rep * 4 + qq) ^ (tp & 7)) << 4));
            a1 += qf[qq*4+0]*tv.x + qf[qq*4+1]*tv.y + qf[qq*4+2]*tv.z + qf[qq*4+3]*tv.w;
        }
        a1 += __shfl_xor(a1, 16, 64);
        a1 += __shfl_xor(a1, 32, 64);      // full logit (x0.125 pre-folded), replicated
        float mx = a1;
        #pragma unroll
        for (int msk = 1; msk < 16; msk <<= 1) mx = fmaxf(mx, __shfl_xor(mx, msk, 64));
        const float ev = __expf(a1 - mx);
        float sm = ev;
        #pragma unroll
        for (int msk = 1; msk < 16; msk <<= 1) sm += __shfl_xor(sm, msk, 64);
        const float pw = ev / sm;
        // PV: lane owns d = lane
        float o = 0.f;
        #pragma unroll
        for (int t = 0; t < 16; ++t) {
            const float wt = __shfl(pw, t, 64);   // lane t holds t'=t
            const float tv = *reinterpret_cast<const float*>(
                tb + t * 256 + ((pvch ^ (t & 7)) << 4) + pvsub * 4);
            o += wt * tv;
        }
        wtfb[(size_t)(tok0 + row) * 512 + n0 + lane] = f2bf(o);
    }
}

// ---------------- GEMM2: out = x + wtf @ wvoT + bvo ----------------

__global__ __launch_bounds__(256) void kG2(
    const unsigned short* __restrict__ A,
    const unsigned short* __restrict__ Bt,
    const float* __restrict__ bias,
    const float* __restrict__ resid,
    float* __restrict__ out)
{
    __shared__ __align__(16) unsigned short Asm[2][128 * 64];
    __shared__ __align__(16) unsigned short Bsm[2][64 * 64];
    const int tid = threadIdx.x;
    const int hw = blockIdx.x;
    const int logical = (hw & 7) * 64 + (hw >> 3);
    const int mt = logical >> 3, nt = logical & 7;
    const int tok0 = mt * 128, n0 = nt * 64;
    const int w = tid >> 6, lane = tid & 63;
    const int wr = w >> 1, wc = w & 1;
    const int lrow = lane & 15, lk = lane >> 4;

    float pb[2];
    float rr[2][4][4];
    #pragma unroll
    for (int n = 0; n < 2; ++n) {
        const int ocol = n0 + wc * 32 + n * 16 + lrow;
        pb[n] = bias[ocol];
        #pragma unroll
        for (int m = 0; m < 4; ++m)
            #pragma unroll
            for (int r = 0; r < 4; ++r) {
                const int orow = tok0 + wr * 64 + m * 16 + lk * 4 + r;
                rr[n][m][r] = resid[(size_t)orow * 512 + ocol];
            }
    }

    const int srowA[4] = { (tid + 0) >> 3, (tid + 256) >> 3, (tid + 512) >> 3, (tid + 768) >> 3 };
    const int sc8 = tid & 7;
    auto STAGE = [&](int buf, int k0) {
        #pragma unroll
        for (int i = 0; i < 4; ++i) {
            const int f = tid + i * 256;
            const int row = srowA[i];
            const int c8s = sc8 ^ (row & 7);
            gl_lds16(A + (size_t)(tok0 + row) * 512 + k0 + c8s * 8,
                     (char*)&Asm[buf][0] + f * 16);
        }
        #pragma unroll
        for (int i = 0; i < 2; ++i) {
            const int f = tid + i * 256;
            const int row = f >> 3;
            const int c8s = sc8 ^ (row & 7);
            gl_lds16(Bt + (size_t)(n0 + row) * 512 + k0 + c8s * 8,
                     (char*)&Bsm[buf][0] + f * 16);
        }
    };

    f32x4 acc[4][2] = {};
    STAGE(0, 0);
    __syncthreads();
    for (int it = 0; it < 8; ++it) {
        const int cur = it & 1;
        if (it < 7) STAGE(cur ^ 1, (it + 1) * 64);
        #pragma unroll
        for (int kk = 0; kk < 2; ++kk) {
            short8 a[4], b[2];
            #pragma unroll
            for (int m = 0; m < 4; ++m) {
                const int r = wr * 64 + m * 16 + lrow;
                const int byte = (r * 128 + kk * 64 + lk * 16) ^ ((r & 7) << 4);
                a[m] = *reinterpret_cast<const short8*>((const char*)&Asm[cur][0] + byte);
            }
            #pragma unroll
            for (int n = 0; n < 2; ++n) {
                const int r = wc * 32 + n * 16 + lrow;
                const int byte = (r * 128 + kk * 64 + lk * 16) ^ ((r & 7) << 4);
                b[n] = *reinterpret_cast<const short8*>((const char*)&Bsm[cur][0] + byte);
            }
            #pragma unroll
            for (int m = 0; m < 4; ++m)
                #pragma unroll
                for (int n = 0; n < 2; ++n)
                    acc[m][n] = __builtin_amdgcn_mfma_f32_16x16x32_bf16(
                        a[m], b[n], acc[m][n], 0, 0, 0);
        }
        __syncthreads();
    }
    #pragma unroll
    for (int n = 0; n < 2; ++n) {
        const int ocol = n0 + wc * 32 + n * 16 + lrow;
        #pragma unroll
        for (int m = 0; m < 4; ++m) {
            #pragma unroll
            for (int r = 0; r < 4; ++r) {
                const int orow = tok0 + wr * 64 + m * 16 + lk * 4 + r;
                out[(size_t)orow * 512 + ocol] = acc[m][n][r] + pb[n] + rr[n][m][r];
            }
        }
    }
}

extern "C" void kernel_launch(void* const* d_in, const int* in_sizes, int n_in,
                              void* d_out, int out_size, void* d_ws, size_t ws_size,
                              hipStream_t stream) {
    const float* x      = (const float*)d_in[0];
    const float* track  = (const float*)d_in[1];
    const float* nscale = (const float*)d_in[2];
    const float* wq     = (const float*)d_in[3];
    const float* bq     = (const float*)d_in[4];
    const float* wk     = (const float*)d_in[5];
    // d_in[6] = bk: constant over t per head -> softmax-invariant, omitted exactly
    const float* wv     = (const float*)d_in[7];
    const float* bv     = (const float*)d_in[8];
    const float* wo     = (const float*)d_in[9];
    const float* bo     = (const float*)d_in[10];
    float* buf = (float*)d_out;

    char* ws = (char*)d_ws;
    unsigned short* xnb  = (unsigned short*)ws;                // 8 MB
    unsigned short* wtfb = (unsigned short*)(ws + 8388608);    // 8 MB
    unsigned short* wqkT = (unsigned short*)(ws + 16777216);   // 512 KB
    unsigned short* wvoT = (unsigned short*)(ws + 17301504);   // 512 KB
    float* bqk = (float*)(ws + 17825792);                      // 2 KB
    float* bvo = (float*)(ws + 17827840);                      // 2 KB

    kprep<<<192 + NTOK / 4, 256, 0, stream>>>(x, nscale, wq, bq, wk, wv, bv, wo, bo,
                                              wqkT, bqk, wvoT, bvo, xnb);
    kFA<<<512, 256, 0, stream>>>(xnb, wqkT, bqk, track, wtfb);
    kG2<<<512, 256, 0, stream>>>(wtfb, wvoT, bvo, x, buf);
}

// Round 10
// 51.486 us; speedup vs baseline: 1.4520x; 1.4520x over previous
//
#include <hip/hip_runtime.h>
#include <math.h>

// TrackCrossAttention, algebraically restructured (round-6 structure + k3 XCD swizzle):
//   wqkT[j=h*64+d][i] = sum_e wq[i][h*64+e]*wk[d][h*64+e]   (bf16, transposed)
//   bqk[h*64+d]       = sum_e bq[h*64+e]*wk[d][h*64+e]
//   wvoT[j][h*64+d]   = sum_e wv[d][h*64+e]*wo[h*64+e][j]   (bf16, transposed)
//   bvo[j]            = sum_e bv[e]*wo[e][j] + bo[j]
// Pipeline (4 kernels):
//   kprep: [bid<64] wqkT/bqk  [64..127] wvoT  [128..191] bvo  [192+] RMSNorm->xn bf16
//   kG<0>: qw = xn @ wqk + bqk -> bf16 (ws)      [MFMA, dbuf prefetch, XCD swizzle]
//   k3   : logits/softmax/wtf -> wtf bf16 (ws)   [2 tok/block, XCD-chunked swizzle]
//   kG<1>: out = x + wtf @ wvo + bvo -> f32 buf  [MFMA, resid reg-prefetch]

#define NTOK 8192

typedef __attribute__((ext_vector_type(8))) short short8;
typedef __attribute__((ext_vector_type(8))) unsigned short ushort8;
typedef __attribute__((ext_vector_type(4))) unsigned short ushort4v;
typedef __attribute__((ext_vector_type(4))) float f32x4;

__device__ __forceinline__ unsigned short f2bf(float f) {
    unsigned int u = __float_as_uint(f);
    unsigned int r = (u + 0x7fffu + ((u >> 16) & 1u)) >> 16;
    return (unsigned short)r;
}
__device__ __forceinline__ float bf2f(unsigned short s) {
    return __uint_as_float(((unsigned int)s) << 16);
}

__device__ __forceinline__ void gl_lds16(const void* g, void* l) {
    __builtin_amdgcn_global_load_lds(
        (const __attribute__((address_space(1))) unsigned int*)g,
        (__attribute__((address_space(3))) unsigned int*)l,
        16, 0, 0);
}

// ---------------- fused prep: weight folding + RMSNorm ----------------

__global__ __launch_bounds__(256) void kprep(
    const float* __restrict__ x, const float* __restrict__ nscale,
    const float* __restrict__ wq, const float* __restrict__ bq,
    const float* __restrict__ wk, const float* __restrict__ wv,
    const float* __restrict__ bv, const float* __restrict__ wo,
    const float* __restrict__ bo,
    unsigned short* __restrict__ wqkT, float* __restrict__ bqk,
    unsigned short* __restrict__ wvoT, float* __restrict__ bvo,
    unsigned short* __restrict__ xnb)
{
    const int bid = blockIdx.x;
    const int t = threadIdx.x;
    if (bid < 64) {
        __shared__ float wkL[64][65];
        __shared__ float wqL[64][65];
        const int h = bid >> 3;
        const int i0 = (bid & 7) * 64;
        #pragma unroll
        for (int i = 0; i < 16; ++i) {
            const int idx = t + i * 256;
            const int d = idx >> 6, e = idx & 63;
            wkL[d][e] = wk[(size_t)d * 512 + h * 64 + e];
            wqL[d][e] = wq[(size_t)(i0 + d) * 512 + h * 64 + e];
        }
        __syncthreads();
        const int d = t & 63, ig = t >> 6;
        float acc[16];
        #pragma unroll
        for (int ii = 0; ii < 16; ++ii) acc[ii] = 0.f;
        for (int e = 0; e < 64; ++e) {
            const float kv = wkL[d][e];
            #pragma unroll
            for (int ii = 0; ii < 16; ++ii)
                acc[ii] += kv * wqL[ig * 16 + ii][e];
        }
        #pragma unroll
        for (int ii = 0; ii < 16; ++ii)
            wqkT[(size_t)(h * 64 + d) * 512 + i0 + ig * 16 + ii] = f2bf(acc[ii]);
        if (((bid & 7) == 0) && ig == 0) {
            float a = 0.f;
            #pragma unroll
            for (int e = 0; e < 64; ++e) a += bq[h * 64 + e] * wkL[d][e];
            bqk[h * 64 + d] = a;
        }
    } else if (bid < 128) {
        __shared__ float wvL[64][65];
        __shared__ float woL[64][65];
        const int b2 = bid - 64;
        const int h = b2 >> 3;
        const int j0 = (b2 & 7) * 64;
        #pragma unroll
        for (int i = 0; i < 16; ++i) {
            const int idx = t + i * 256;
            const int a = idx >> 6, b = idx & 63;
            wvL[a][b] = wv[(size_t)a * 512 + h * 64 + b];
            woL[a][b] = wo[(size_t)(h * 64 + a) * 512 + j0 + b];
        }
        __syncthreads();
        const int jloc = t & 63, dg = t >> 6;
        float acc[16];
        #pragma unroll
        for (int dd = 0; dd < 16; ++dd) acc[dd] = 0.f;
        for (int e = 0; e < 64; ++e) {
            const float b = woL[e][jloc];
            #pragma unroll
            for (int dd = 0; dd < 16; ++dd)
                acc[dd] += wvL[dg * 16 + dd][e] * b;
        }
        #pragma unroll
        for (int dd = 0; dd < 16; ++dd)
            wvoT[(size_t)(j0 + jloc) * 512 + h * 64 + dg * 16 + dd] = f2bf(acc[dd]);
    } else if (bid < 192) {
        const int b3 = bid - 128;
        const int j = b3 * 8 + (t >> 5);
        const int l = t & 31;
        float p = 0.f;
        #pragma unroll 4
        for (int e = l; e < 512; e += 32) p += bv[e] * wo[(size_t)e * 512 + j];
        #pragma unroll
        for (int m = 1; m < 32; m <<= 1) p += __shfl_xor(p, m, 64);
        if (l == 0) bvo[j] = bo[j] + p;
    } else {
        const int row = (bid - 192) * 4 + (t >> 6);
        const int lane = t & 63;
        const float* xr = x + (size_t)row * 512 + lane * 8;
        const float4 v0 = *reinterpret_cast<const float4*>(xr);
        const float4 v1 = *reinterpret_cast<const float4*>(xr + 4);
        float s = v0.x*v0.x + v0.y*v0.y + v0.z*v0.z + v0.w*v0.w
                + v1.x*v1.x + v1.y*v1.y + v1.z*v1.z + v1.w*v1.w;
        #pragma unroll
        for (int m = 1; m < 64; m <<= 1) s += __shfl_xor(s, m, 64);
        const float r = rsqrtf(s * (1.f / 512.f) + 1e-6f);
        const float4 s0 = *reinterpret_cast<const float4*>(nscale + lane * 8);
        const float4 s1 = *reinterpret_cast<const float4*>(nscale + lane * 8 + 4);
        ushort8 o;
        o[0] = f2bf(v0.x * r * s0.x); o[1] = f2bf(v0.y * r * s0.y);
        o[2] = f2bf(v0.z * r * s0.z); o[3] = f2bf(v0.w * r * s0.w);
        o[4] = f2bf(v1.x * r * s1.x); o[5] = f2bf(v1.y * r * s1.y);
        o[6] = f2bf(v1.z * r * s1.z); o[7] = f2bf(v1.w * r * s1.w);
        *reinterpret_cast<ushort8*>(xnb + (size_t)row * 512 + lane * 8) = o;
    }
}

// ---------------- MFMA GEMM: [8192x512] x [512x512] ----------------
// 128x64 tile, BK=64, double-buffered LDS prefetch, XCD-swizzled grid.
// MODE 0: out bf16, no resid.  MODE 1: out f32 + resid (register-prefetched).

template<int MODE>
__global__ __launch_bounds__(256) void kG(
    const unsigned short* __restrict__ A,
    const unsigned short* __restrict__ Bt,
    const float* __restrict__ bias,
    const float* __restrict__ resid,
    void* __restrict__ outp)
{
    __shared__ __align__(16) unsigned short Asm[2][128 * 64];
    __shared__ __align__(16) unsigned short Bsm[2][64 * 64];
    const int tid = threadIdx.x;
    // XCD-aware bijective swizzle: 8 n-blocks of one m-panel -> same XCD L2
    const int hw = blockIdx.x;
    const int logical = (hw & 7) * 64 + (hw >> 3);
    const int mt = logical >> 3, nt = logical & 7;
    const int tok0 = mt * 128, n0 = nt * 64;
    const int w = tid >> 6, lane = tid & 63;
    const int wr = w >> 1, wc = w & 1;
    const int lrow = lane & 15, lk = lane >> 4;

    // ---- epilogue operand prefetch (fly under the K-loop) ----
    float pb[2];
    float rr[2][4][4];   // [n][m][r], MODE 1 only
    #pragma unroll
    for (int n = 0; n < 2; ++n) {
        const int ocol = n0 + wc * 32 + n * 16 + lrow;
        pb[n] = bias[ocol];
        if (MODE == 1) {
            #pragma unroll
            for (int m = 0; m < 4; ++m)
                #pragma unroll
                for (int r = 0; r < 4; ++r) {
                    const int orow = tok0 + wr * 64 + m * 16 + lk * 4 + r;
                    rr[n][m][r] = resid[(size_t)orow * 512 + ocol];
                }
        }
    }

    // per-thread staging indices (rule #21: linear LDS dest, inverse-swizzled src)
    const int srowA[4] = { (tid + 0) >> 3, (tid + 256) >> 3, (tid + 512) >> 3, (tid + 768) >> 3 };
    const int sc8 = tid & 7;

    auto STAGE = [&](int buf, int k0) {
        #pragma unroll
        for (int i = 0; i < 4; ++i) {
            const int f = tid + i * 256;
            const int row = srowA[i];
            const int c8s = sc8 ^ (row & 7);
            gl_lds16(A + (size_t)(tok0 + row) * 512 + k0 + c8s * 8,
                     (char*)&Asm[buf][0] + f * 16);
        }
        #pragma unroll
        for (int i = 0; i < 2; ++i) {
            const int f = tid + i * 256;
            const int row = f >> 3;
            const int c8s = sc8 ^ (row & 7);
            gl_lds16(Bt + (size_t)(n0 + row) * 512 + k0 + c8s * 8,
                     (char*)&Bsm[buf][0] + f * 16);
        }
    };

    f32x4 acc[4][2] = {};
    STAGE(0, 0);
    __syncthreads();
    for (int it = 0; it < 8; ++it) {
        const int cur = it & 1;
        if (it < 7) STAGE(cur ^ 1, (it + 1) * 64);
        #pragma unroll
        for (int kk = 0; kk < 2; ++kk) {
            short8 a[4], b[2];
            #pragma unroll
            for (int m = 0; m < 4; ++m) {
                const int r = wr * 64 + m * 16 + lrow;
                const int byte = (r * 128 + kk * 64 + lk * 16) ^ ((r & 7) << 4);
                a[m] = *reinterpret_cast<const short8*>((const char*)&Asm[cur][0] + byte);
            }
            #pragma unroll
            for (int n = 0; n < 2; ++n) {
                const int r = wc * 32 + n * 16 + lrow;
                const int byte = (r * 128 + kk * 64 + lk * 16) ^ ((r & 7) << 4);
                b[n] = *reinterpret_cast<const short8*>((const char*)&Bsm[cur][0] + byte);
            }
            #pragma unroll
            for (int m = 0; m < 4; ++m)
                #pragma unroll
                for (int n = 0; n < 2; ++n)
                    acc[m][n] = __builtin_amdgcn_mfma_f32_16x16x32_bf16(
                        a[m], b[n], acc[m][n], 0, 0, 0);
        }
        __syncthreads();   // drains vmcnt(0): prefetch issued above has flown under MFMA
    }
    #pragma unroll
    for (int n = 0; n < 2; ++n) {
        const int ocol = n0 + wc * 32 + n * 16 + lrow;
        #pragma unroll
        for (int m = 0; m < 4; ++m) {
            #pragma unroll
            for (int r = 0; r < 4; ++r) {
                const int orow = tok0 + wr * 64 + m * 16 + lk * 4 + r;
                float v = acc[m][n][r] + pb[n];
                if (MODE == 0) {
                    ((unsigned short*)outp)[(size_t)orow * 512 + ocol] = f2bf(v);
                } else {
                    v += rr[n][m][r];
                    ((float*)outp)[(size_t)orow * 512 + ocol] = v;
                }
            }
        }
    }
}

// ---------------- attention core: 2 tokens/block, XCD-chunked swizzle ----------------
// Swizzle: XCD k (hw%8) handles logical blocks [k*512,(k+1)*512) = 1024 contiguous
// tokens, whose track slice = 16 rows x 256KB = 4MB = exactly one XCD L2.

__global__ __launch_bounds__(256) void k3_attn(
    const float* __restrict__ track, const unsigned short* __restrict__ qwb,
    unsigned short* __restrict__ wtfb)
{
    __shared__ __align__(16) float tf[2][16][68];
    __shared__ __align__(16) float qwl[2][8][68];
    __shared__ float lw[2][8][16];
    const int tid = threadIdx.x;
    const int tok = tid >> 7;         // 0..1
    const int t2 = tid & 127;
    const int hw = blockIdx.x;
    const int logical = (hw & 7) * 512 + (hw >> 3);   // 4096 blocks, 4096%8==0 bijective
    const int token = logical * 2 + tok;
    const int b = token >> 12;        // C = 4096
    const int c = token & 4095;
    #pragma unroll
    for (int i = 0; i < 2; ++i) {
        const int f = t2 + i * 128;   // 0..255
        const int row = f >> 4, d4 = (f & 15) * 4;
        *reinterpret_cast<float4*>(&tf[tok][row][d4]) =
            *reinterpret_cast<const float4*>(track + ((size_t)(b * 16 + row) * 4096 + c) * 64 + d4);
    }
    if (t2 < 64) {
        const ushort8 q = *reinterpret_cast<const ushort8*>(qwb + (size_t)token * 512 + t2 * 8);
        #pragma unroll
        for (int j = 0; j < 8; ++j) {
            const int idx = t2 * 8 + j;
            qwl[tok][idx >> 6][idx & 63] = bf2f(q[j]);
        }
    }
    __syncthreads();
    {
        const int h = t2 >> 4, tt = t2 & 15;
        float acc = 0.f;
        #pragma unroll
        for (int d16 = 0; d16 < 16; ++d16) {
            const float4 qv = *reinterpret_cast<const float4*>(&qwl[tok][h][d16 * 4]);
            const float4 tv = *reinterpret_cast<const float4*>(&tf[tok][tt][d16 * 4]);
            acc += qv.x * tv.x + qv.y * tv.y + qv.z * tv.z + qv.w * tv.w;
        }
        float lg = acc * 0.125f;      // 1/sqrt(64)
        float mx = lg;
        #pragma unroll
        for (int m = 1; m < 16; m <<= 1) mx = fmaxf(mx, __shfl_xor(mx, m, 64));
        const float ev = __expf(lg - mx);
        float sum = ev;
        #pragma unroll
        for (int m = 1; m < 16; m <<= 1) sum += __shfl_xor(sum, m, 64);
        lw[tok][h][tt] = ev / sum;
    }
    __syncthreads();
    {
        const int h = t2 >> 4;
        const int d0 = (t2 & 15) * 4;
        float o0 = 0.f, o1 = 0.f, o2 = 0.f, o3 = 0.f;
        #pragma unroll
        for (int t = 0; t < 16; ++t) {
            const float wgt = lw[tok][h][t];
            const float4 tv = *reinterpret_cast<const float4*>(&tf[tok][t][d0]);
            o0 += wgt * tv.x; o1 += wgt * tv.y; o2 += wgt * tv.z; o3 += wgt * tv.w;
        }
        ushort4v ov;
        ov[0] = f2bf(o0); ov[1] = f2bf(o1); ov[2] = f2bf(o2); ov[3] = f2bf(o3);
        *reinterpret_cast<ushort4v*>(wtfb + (size_t)token * 512 + t2 * 4) = ov;
    }
}

extern "C" void kernel_launch(void* const* d_in, const int* in_sizes, int n_in,
                              void* d_out, int out_size, void* d_ws, size_t ws_size,
                              hipStream_t stream) {
    const float* x      = (const float*)d_in[0];
    const float* track  = (const float*)d_in[1];
    const float* nscale = (const float*)d_in[2];
    const float* wq     = (const float*)d_in[3];
    const float* bq     = (const float*)d_in[4];
    const float* wk     = (const float*)d_in[5];
    // d_in[6] = bk: constant over t per head -> softmax-invariant, omitted exactly
    const float* wv     = (const float*)d_in[7];
    const float* bv     = (const float*)d_in[8];
    const float* wo     = (const float*)d_in[9];
    const float* bo     = (const float*)d_in[10];
    float* buf = (float*)d_out;

    char* ws = (char*)d_ws;
    unsigned short* xnb  = (unsigned short*)ws;                // 8 MB (xn)
    unsigned short* qwb  = (unsigned short*)(ws + 8388608);    // 8 MB (qw bf16)
    unsigned short* wtfb = (unsigned short*)(ws + 16777216);   // 8 MB (wtf bf16)
    unsigned short* wqkT = (unsigned short*)(ws + 25165824);   // 512 KB
    unsigned short* wvoT = (unsigned short*)(ws + 25690112);   // 512 KB
    float* bqk = (float*)(ws + 26214400);                      // 2 KB
    float* bvo = (float*)(ws + 26216448);                      // 2 KB

    kprep<<<192 + NTOK / 4, 256, 0, stream>>>(x, nscale, wq, bq, wk, wv, bv, wo, bo,
                                              wqkT, bqk, wvoT, bvo, xnb);
    kG<0><<<512, 256, 0, stream>>>(xnb, wqkT, bqk, nullptr, qwb);
    k3_attn<<<NTOK / 2, 256, 0, stream>>>(track, qwb, wtfb);
    kG<1><<<512, 256, 0, stream>>>(wtfb, wvoT, bvo, x, buf);
}